// Round 6
// baseline (363.155 us; speedup 1.0000x reference)
//
#include <hip/hip_runtime.h>

#define DIM 160
#define SLICE (DIM * DIM)
#define TH 16
#define TW 16
#define CD 20   // output slices per block chunk; 160/CD = 8 chunks per batch
#define NS (CD + 8)   // input slices per chunk (28); iterations: s = 0..NS

// Fused LNCC, separable w -> h -> d. History:
//  R0-R2: 3-barrier LDS pipeline, LDS-pipe-bound (~85% busy by op model).
//  R4: w-sum in registers at load time -> LDS ~42% busy, time unchanged:
//      latency-bound. R5: non-vmcnt-draining barriers -> no change; the
//      drain wasn't the stall. Model: ~2 co-resident blocks/CU (occupancy
//      20-28% every round) cannot hide the ~2000cy/slice dependency chain;
//      loads issued only ~200cy before use; ~1.78 TB/s is an ISSUE-rate
//      ceiling (Little's law), not an HBM ceiling.
//  This version attacks exposed latency from both sides:
//   - deep prefetch: carried-load registers double-buffered (parity sets,
//     compile-time via 18-deep unroll; 18 = 0 mod 9 keeps ring phase static).
//     Loads are issued a FULL iteration before use; 12 in flight per loader.
//   - CD 40->20: 1600 blocks = 6.25/CU available; launch_bounds(256,4)
//     (VGPR<=128) allows 4 blocks/CU resident (2x current co-residency).
// Per input slice z, 2 barriers:
//   Phase A: all 256 threads ring-update from U(z-1) (5 b32 reads);
//            loaders t>=160 (96 = 24 halo rows x 4 col-quads) compute
//            5-channel w-sums from float4s loaded ~1 iteration ago (named
//            scalars, parity set) and write H (10 b128 wave-issues).
//   Phase B: wave0 lanes t<40 (5ch x 4quad x 2half) h-sum H->U via register
//            slide (16 read + 8 write b128); loaders issue slice s+2's
//            6 float4 global loads into the just-consumed parity set.
#define HIDX(c,i,j) ((c)*680 + (i)*28 + (j))   // H: 24x28 plane (16 used + pad)
#define UIDX(c,i,j) ((c)*260 + (i)*16 + (j))   // U: 16x16 plane (+4 pad)

// 9-tap sliding window over 12 consecutive values -> 4 outputs
#define WSLIDE(dst, V0,V1,V2,V3,V4,V5,V6,V7,V8,V9,V10,V11) do {            \
    float s_ = (V0)+(V1)+(V2)+(V3)+(V4)+(V5)+(V6)+(V7)+(V8);               \
    float4 o_; o_.x = s_;                                                  \
    s_ += (V9)  - (V0); o_.y = s_;                                         \
    s_ += (V10) - (V1); o_.z = s_;                                         \
    s_ += (V11) - (V2); o_.w = s_;                                         \
    (dst) = o_; } while (0)

// Barrier that does NOT drain vmcnt: LDS producers/consumers are ordered by
// lgkmcnt(0); global loads issued before it stay in flight (T4 pattern).
static __device__ __forceinline__ void barrier_novm()
{
    asm volatile("s_waitcnt lgkmcnt(0)" ::: "memory");
    __builtin_amdgcn_s_barrier();
    asm volatile("" ::: "memory");
}

__global__ __launch_bounds__(256, 4)
void lncc_kernel(const float* __restrict__ x, const float* __restrict__ y,
                 float* __restrict__ out)
{
    __shared__ __align__(16) float H[5 * 680];
    __shared__ __align__(16) float U[5 * 260];
    __shared__ float wsum[4];

    const int t  = threadIdx.x;
    const int w0 = blockIdx.x * TW;
    const int h0 = blockIdx.y * TH;
    const int bz = blockIdx.z;
    const int b   = bz >> 3;              // batch
    const int zo0 = (bz & 7) * CD;        // first output slice of chunk

    const float* xb = x + (size_t)b * (DIM * SLICE);
    const float* yb = y + (size_t)b * (DIM * SLICE);

    // ---- loader role (t in [160,256)): (halo row lrw, output col-quad lq) ----
    const int lt  = t - 160;              // 0..95
    const int lrw = lt >> 2;              // 0..23
    const int lq  = lt & 3;               // 0..3
    const int ghr = min(max(h0 - 4 + lrw, 0), DIM - 1);
    const int rowoff = ghr * DIM;
    const int gws = w0 + 4 * lq - 4;      // first of 12 input cols (aligned)
    // quad 1 (cols gws+4..gws+7) is always in-bounds; quads 0/2 clamp at edges
    const bool ok0 = (gws >= 0);
    const bool ok2 = (gws + 8 <= DIM - 4);
    const int jj = 4 * lq;

    // ---- h-sum role (t < 40): (channel hcc, col-quad hq, row-half hh) ----
    const int hcc = t >> 3;               // 0..4
    const int hq  = (t >> 1) & 3;         // 0..3
    const int hh  = t & 1;                // 0..1
    const int hr0 = hh * 8;
    const int hjj = 4 * hq;

    // ---- ring role: one output column each ----
    const int i4 = t >> 4;
    const int j4 = t & 15;

    float hist[9][5];                     // register ring (constant indices)
    float rs[5] = {0.f, 0.f, 0.f, 0.f, 0.f};
    float acc = 0.f;

    // two parity sets of carried loads (48 VGPR in loader threads)
    float4 eX0, eX1, eX2, eY0, eY1, eY2;  // even-s slices
    float4 oX0, oX1, oX2, oY0, oY1, oY2;  // odd-s slices

    auto issue_into = [&](int zsl, float4& X0, float4& X1, float4& X2,
                                   float4& Y0, float4& Y1, float4& Y2) {
        const float* xs = xb + (size_t)zsl * SLICE + rowoff;
        const float* ys = yb + (size_t)zsl * SLICE + rowoff;
        X1 = *reinterpret_cast<const float4*>(xs + gws + 4);
        Y1 = *reinterpret_cast<const float4*>(ys + gws + 4);
        if (ok0) {
            X0 = *reinterpret_cast<const float4*>(xs + gws);
            Y0 = *reinterpret_cast<const float4*>(ys + gws);
        } else {
            const float v = xs[0];       X0 = make_float4(v, v, v, v);
            const float w = ys[0];       Y0 = make_float4(w, w, w, w);
        }
        if (ok2) {
            X2 = *reinterpret_cast<const float4*>(xs + gws + 8);
            Y2 = *reinterpret_cast<const float4*>(ys + gws + 8);
        } else {
            const float v = xs[DIM - 1]; X2 = make_float4(v, v, v, v);
            const float w = ys[DIM - 1]; Y2 = make_float4(w, w, w, w);
        }
    };

    auto wsums_from = [&](const float4& X0, const float4& X1, const float4& X2,
                          const float4& Y0, const float4& Y1, const float4& Y2) {
        float4 o;
        WSLIDE(o, X0.x,X0.y,X0.z,X0.w, X1.x,X1.y,X1.z,X1.w, X2.x,X2.y,X2.z,X2.w);
        *reinterpret_cast<float4*>(&H[HIDX(0, lrw, jj)]) = o;
        WSLIDE(o, Y0.x,Y0.y,Y0.z,Y0.w, Y1.x,Y1.y,Y1.z,Y1.w, Y2.x,Y2.y,Y2.z,Y2.w);
        *reinterpret_cast<float4*>(&H[HIDX(1, lrw, jj)]) = o;
        float4 a0 = X0 * X0, a1 = X1 * X1, a2 = X2 * X2;
        WSLIDE(o, a0.x,a0.y,a0.z,a0.w, a1.x,a1.y,a1.z,a1.w, a2.x,a2.y,a2.z,a2.w);
        *reinterpret_cast<float4*>(&H[HIDX(2, lrw, jj)]) = o;
        a0 = Y0 * Y0; a1 = Y1 * Y1; a2 = Y2 * Y2;
        WSLIDE(o, a0.x,a0.y,a0.z,a0.w, a1.x,a1.y,a1.z,a1.w, a2.x,a2.y,a2.z,a2.w);
        *reinterpret_cast<float4*>(&H[HIDX(3, lrw, jj)]) = o;
        a0 = X0 * Y0; a1 = X1 * Y1; a2 = X2 * Y2;
        WSLIDE(o, a0.x,a0.y,a0.z,a0.w, a1.x,a1.y,a1.z,a1.w, a2.x,a2.y,a2.z,a2.w);
        *reinterpret_cast<float4*>(&H[HIDX(4, lrw, jj)]) = o;
    };

    const int zfirst = zo0 - 4;           // NS input slices: zfirst .. zfirst+NS-1
    auto zclamp = [&](int s) { return min(max(zfirst + s, 0), DIM - 1); };
    if (t >= 160) {
        issue_into(zclamp(0), eX0, eX1, eX2, eY0, eY1, eY2);
        issue_into(zclamp(1), oX0, oX1, oX2, oY0, oY1, oY2);
    }

    // iteration s: A = ring(slice s-1 via U) + w-sum/write H(slice s);
    //              B = h-sum H(s)->U(s) + issue loads for slice s+2 into the
    //                  parity set consumed this phase A.
    // s = NS is the ring-only epilogue. 18-unroll: ring phase (s mod 9 = p
    // mod 9, since 18 = 0 mod 9) AND load parity (s&1 = p&1) compile-time.
    for (int base = 0; base < 36; base += 18) {
        #pragma unroll
        for (int p = 0; p < 18; ++p) {
            const int s = base + p;
            if (s <= NS) {
                // ---- Phase A ----
                if (s >= 1) {             // ring for slice s-1 (reads U(s-1))
                    const int cp = (p + 8) % 9;   // (s-1) mod 9, compile-time
                    float u[5];
                    #pragma unroll
                    for (int c = 0; c < 5; ++c) {
                        u[c] = U[UIDX(c, i4, j4)];
                        rs[c] += u[c];
                        hist[cp][c] = u[c];
                    }
                    if (s >= 9) {
                        const float inv = 1.0f / 729.0f;
                        const float xm = rs[0] * inv, ym = rs[1] * inv;
                        const float x2 = rs[2] * inv, y2 = rs[3] * inv;
                        const float xy = rs[4] * inv;
                        const float cross = xy - xm * ym;
                        const float vx = x2 - xm * xm;
                        const float vy = y2 - ym * ym;
                        acc += cross * cross / (vx * vy + 1e-5f);
                        const int po = (cp + 1) % 9;  // slice leaving window
                        #pragma unroll
                        for (int c = 0; c < 5; ++c)
                            rs[c] -= hist[po][c];
                    }
                }
                if (s <= NS - 1 && t >= 160) {   // w-sums of parity set -> H
                    if ((p & 1) == 0) wsums_from(eX0, eX1, eX2, eY0, eY1, eY2);
                    else              wsums_from(oX0, oX1, oX2, oY0, oY1, oY2);
                }
                barrier_novm();
                // ---- Phase B ----
                if (s <= NS - 1 && t < 40) {     // h-sum H(s) -> U(s), reg slide
                    float4 sum = make_float4(0.f, 0.f, 0.f, 0.f);
                    #pragma unroll
                    for (int k = 0; k < 9; ++k)
                        sum += *reinterpret_cast<const float4*>(&H[HIDX(hcc, hr0 + k, hjj)]);
                    *reinterpret_cast<float4*>(&U[UIDX(hcc, hr0, hjj)]) = sum;
                    #pragma unroll
                    for (int m = 1; m < 8; ++m) {
                        sum += *reinterpret_cast<const float4*>(&H[HIDX(hcc, hr0 + m + 8, hjj)])
                             - *reinterpret_cast<const float4*>(&H[HIDX(hcc, hr0 + m - 1, hjj)]);
                        *reinterpret_cast<float4*>(&U[UIDX(hcc, hr0 + m, hjj)]) = sum;
                    }
                }
                if (s <= NS - 3 && t >= 160) {   // loads for slice s+2 (same parity)
                    if ((p & 1) == 0) issue_into(zclamp(s + 2), eX0, eX1, eX2, eY0, eY1, eY2);
                    else              issue_into(zclamp(s + 2), oX0, oX1, oX2, oY0, oY1, oY2);
                }
                barrier_novm();              // loads stay in flight across this
            }
        }
    }

    // ---- block reduction: wave shuffle, then 4 partials via LDS ----
    __syncthreads();                      // full drain before reuse of LDS
    #pragma unroll
    for (int off = 32; off > 0; off >>= 1)
        acc += __shfl_down(acc, off, 64);
    const int wave = t >> 6;
    if ((t & 63) == 0) wsum[wave] = acc;
    __syncthreads();
    if (t == 0) {
        const float s = wsum[0] + wsum[1] + wsum[2] + wsum[3];
        atomicAdd(out, -s * (1.0f / 8192000.0f));
    }
}

extern "C" void kernel_launch(void* const* d_in, const int* in_sizes, int n_in,
                              void* d_out, int out_size, void* d_ws, size_t ws_size,
                              hipStream_t stream)
{
    const float* x = (const float*)d_in[0];
    const float* y = (const float*)d_in[1];
    float* out = (float*)d_out;

    // d_out is poisoned 0xAA before every call; accumulate atomically on zero
    hipMemsetAsync(out, 0, sizeof(float), stream);

    dim3 grid(DIM / TW, DIM / TH, 2 * (DIM / CD));  // 10 x 10 x 16 = 1600 blocks
    lncc_kernel<<<grid, 256, 0, stream>>>(x, y, out);
}

// Round 7
// 182.329 us; speedup vs baseline: 1.9918x; 1.9918x over previous
//
#include <hip/hip_runtime.h>

#define DIM 160
#define SLICE (DIM * DIM)
#define TH 16
#define TW 16
#define CD 20         // output slices per block chunk; 160/CD = 8 chunks/batch
#define NS (CD + 8)   // 28 input slices; iterations i = 0..NS+1

// Fused LNCC, separable w -> h -> d. Evidence so far:
//  R0-R2: 3-barrier LDS pipeline ~91us (LDS ~83% busy).
//  R4/R5: w-sum at load time, LDS ops -40%, novm barriers -> STILL ~96us;
//         all pipes <45% busy; per-slice critical path ~3600cy vs ~700cy of
//         issue work => barrier-count x latency bound, not throughput bound.
//  R6: deep prefetch via 2x carried regs + launch_bounds(256,4) -> VGPR
//      squeezed to 64, 367MB scratch spills, 3x regression. Register
//      envelope: (256,2), single-buffered carried loads (84 VGPR, no spill).
//  This version: ONE barrier per slice. Software-pipelined roles run
//  concurrently between barriers on disjoint thread groups:
//   iteration i:  ring(slice i-2, reads U[i&1])
//              || loaders: w-sum(slice i) -> H[i&1], then issue loads(i+1)
//              || h-sum threads: H[(i-1)&1] -> U[(i-1)&1]
//              then barrier_novm (loads stay in flight across it).
//  Double-buffered H,U make same-iteration accesses buffer-disjoint; every
//  producer->consumer pair crosses exactly one lgkm-draining barrier.
//  Loads are issued a full iteration (~1000cy) before consumption; x,y
//  (65MB) are L3-resident so steady-state loads are L3/L2 hits.
//  18-deep unroll (18 = 0 mod 9, even) keeps ring phase AND buffer parity
//  compile-time.
#define HP 492        // H plane stride: 24*20 + 12 pad; 12c mod 32 distinct, 16B-aligned
#define HR 20         // H row stride (16 used cols + 4)
#define HIDX(c,i,j) ((c)*HP + (i)*HR + (j))
#define UIDX(c,i,j) ((c)*260 + (i)*16 + (j))   // U: 16x16 plane (+4 pad)

// 9-tap sliding window over 12 consecutive values -> 4 outputs
#define WSLIDE(dst, V0,V1,V2,V3,V4,V5,V6,V7,V8,V9,V10,V11) do {            \
    float s_ = (V0)+(V1)+(V2)+(V3)+(V4)+(V5)+(V6)+(V7)+(V8);               \
    float4 o_; o_.x = s_;                                                  \
    s_ += (V9)  - (V0); o_.y = s_;                                         \
    s_ += (V10) - (V1); o_.z = s_;                                         \
    s_ += (V11) - (V2); o_.w = s_;                                         \
    (dst) = o_; } while (0)

// Barrier that does NOT drain vmcnt: LDS producers/consumers are ordered by
// lgkmcnt(0); global loads issued before it stay in flight (T4 pattern).
static __device__ __forceinline__ void barrier_novm()
{
    asm volatile("s_waitcnt lgkmcnt(0)" ::: "memory");
    __builtin_amdgcn_s_barrier();
    asm volatile("" ::: "memory");
}

__global__ __launch_bounds__(256, 2)
void lncc_kernel(const float* __restrict__ x, const float* __restrict__ y,
                 float* __restrict__ out)
{
    __shared__ __align__(16) float H[2][5 * HP];
    __shared__ __align__(16) float U[2][5 * 260];
    __shared__ float wsum[4];

    const int t  = threadIdx.x;
    const int w0 = blockIdx.x * TW;
    const int h0 = blockIdx.y * TH;
    const int bz = blockIdx.z;
    const int b   = bz >> 3;              // batch
    const int zo0 = (bz & 7) * CD;        // first output slice of chunk

    const float* xb = x + (size_t)b * (DIM * SLICE);
    const float* yb = y + (size_t)b * (DIM * SLICE);

    // ---- loader role (t in [160,256)): (halo row lrw, output col-quad lq) ----
    const int lt  = t - 160;              // 0..95
    const int lrw = lt >> 2;              // 0..23
    const int lq  = lt & 3;               // 0..3
    const int ghr = min(max(h0 - 4 + lrw, 0), DIM - 1);
    const int rowoff = ghr * DIM;
    const int gws = w0 + 4 * lq - 4;      // first of 12 input cols (aligned)
    // quad 1 (cols gws+4..gws+7) is always in-bounds; quads 0/2 clamp at edges
    const bool ok0 = (gws >= 0);
    const bool ok2 = (gws + 8 <= DIM - 4);
    const int jj = 4 * lq;

    // ---- h-sum role (t < 40): (channel hcc, col-quad hq, row-half hh) ----
    const int hcc = t >> 3;               // 0..4
    const int hq  = (t >> 1) & 3;         // 0..3
    const int hh  = t & 1;                // 0..1
    const int hr0 = hh * 8;
    const int hjj = 4 * hq;

    // ---- ring role: one output column each ----
    const int i4 = t >> 4;
    const int j4 = t & 15;

    float hist[9][5];                     // register ring (constant indices)
    float rs[5] = {0.f, 0.f, 0.f, 0.f, 0.f};
    float acc = 0.f;

    // carried loads (24 VGPR, single-buffered -- R4/R5-proven envelope)
    float4 lX0, lX1, lX2, lY0, lY1, lY2;

    auto issue_loads = [&](int zsl) {
        const float* xs = xb + (size_t)zsl * SLICE + rowoff;
        const float* ys = yb + (size_t)zsl * SLICE + rowoff;
        lX1 = *reinterpret_cast<const float4*>(xs + gws + 4);
        lY1 = *reinterpret_cast<const float4*>(ys + gws + 4);
        if (ok0) {
            lX0 = *reinterpret_cast<const float4*>(xs + gws);
            lY0 = *reinterpret_cast<const float4*>(ys + gws);
        } else {
            const float v = xs[0];       lX0 = make_float4(v, v, v, v);
            const float w = ys[0];       lY0 = make_float4(w, w, w, w);
        }
        if (ok2) {
            lX2 = *reinterpret_cast<const float4*>(xs + gws + 8);
            lY2 = *reinterpret_cast<const float4*>(ys + gws + 8);
        } else {
            const float v = xs[DIM - 1]; lX2 = make_float4(v, v, v, v);
            const float w = ys[DIM - 1]; lY2 = make_float4(w, w, w, w);
        }
    };

    auto wsums_to = [&](float* Hb) {
        float4 o;
        WSLIDE(o, lX0.x,lX0.y,lX0.z,lX0.w, lX1.x,lX1.y,lX1.z,lX1.w,
                  lX2.x,lX2.y,lX2.z,lX2.w);
        *reinterpret_cast<float4*>(&Hb[HIDX(0, lrw, jj)]) = o;
        WSLIDE(o, lY0.x,lY0.y,lY0.z,lY0.w, lY1.x,lY1.y,lY1.z,lY1.w,
                  lY2.x,lY2.y,lY2.z,lY2.w);
        *reinterpret_cast<float4*>(&Hb[HIDX(1, lrw, jj)]) = o;
        float4 a0 = lX0 * lX0, a1 = lX1 * lX1, a2 = lX2 * lX2;
        WSLIDE(o, a0.x,a0.y,a0.z,a0.w, a1.x,a1.y,a1.z,a1.w, a2.x,a2.y,a2.z,a2.w);
        *reinterpret_cast<float4*>(&Hb[HIDX(2, lrw, jj)]) = o;
        a0 = lY0 * lY0; a1 = lY1 * lY1; a2 = lY2 * lY2;
        WSLIDE(o, a0.x,a0.y,a0.z,a0.w, a1.x,a1.y,a1.z,a1.w, a2.x,a2.y,a2.z,a2.w);
        *reinterpret_cast<float4*>(&Hb[HIDX(3, lrw, jj)]) = o;
        a0 = lX0 * lY0; a1 = lX1 * lY1; a2 = lX2 * lY2;
        WSLIDE(o, a0.x,a0.y,a0.z,a0.w, a1.x,a1.y,a1.z,a1.w, a2.x,a2.y,a2.z,a2.w);
        *reinterpret_cast<float4*>(&Hb[HIDX(4, lrw, jj)]) = o;
    };

    const int zfirst = zo0 - 4;           // slices 0..NS-1 <-> z = zfirst+...
    auto zclamp = [&](int sl) { return min(max(zfirst + sl, 0), DIM - 1); };
    if (t >= 160) issue_loads(zclamp(0));

    // iteration i: ring(i-2) || w-sum(i)->H[i&1] + issue loads(i+1)
    //              || h-sum H[(i-1)&1] -> U[(i-1)&1]; ONE barrier.
    // i = 0..NS+1. 18-unroll: i&1 == p&1 and (i-2)%9 == (p+7)%9, both static.
    for (int base = 0; base < 36; base += 18) {
        #pragma unroll
        for (int p = 0; p < 18; ++p) {
            const int i = base + p;
            if (i <= NS + 1) {
                // ---- ring: slice i-2 (reads U[i&1], written last iteration)
                if (i >= 2) {
                    const float* Ub = U[p & 1];
                    const int cp = (p + 7) % 9;   // (i-2) mod 9, compile-time
                    float u[5];
                    #pragma unroll
                    for (int c = 0; c < 5; ++c) {
                        u[c] = Ub[UIDX(c, i4, j4)];
                        rs[c] += u[c];
                        hist[cp][c] = u[c];
                    }
                    if (i >= 10) {        // window of 9 slices complete
                        const float inv = 1.0f / 729.0f;
                        const float xm = rs[0] * inv, ym = rs[1] * inv;
                        const float x2 = rs[2] * inv, y2 = rs[3] * inv;
                        const float xy = rs[4] * inv;
                        const float cross = xy - xm * ym;
                        const float vx = x2 - xm * xm;
                        const float vy = y2 - ym * ym;
                        acc += cross * cross / (vx * vy + 1e-5f);
                        const int po = (cp + 1) % 9;  // slice leaving window
                        #pragma unroll
                        for (int c = 0; c < 5; ++c)
                            rs[c] -= hist[po][c];
                    }
                }
                // ---- loaders: w-sum slice i -> H[i&1], then loads for i+1
                if (i <= NS - 1 && t >= 160) {
                    wsums_to(H[p & 1]);
                    if (i <= NS - 2) issue_loads(zclamp(i + 1));
                }
                // ---- h-sum: slice i-1, H[(i-1)&1] -> U[(i-1)&1]
                if (i >= 1 && i <= NS && t < 40) {
                    const float* Hb = H[(p + 1) & 1];
                    float* Ue = U[(p + 1) & 1];
                    float4 sum = make_float4(0.f, 0.f, 0.f, 0.f);
                    #pragma unroll
                    for (int k = 0; k < 9; ++k)
                        sum += *reinterpret_cast<const float4*>(&Hb[HIDX(hcc, hr0 + k, hjj)]);
                    *reinterpret_cast<float4*>(&Ue[UIDX(hcc, hr0, hjj)]) = sum;
                    #pragma unroll
                    for (int m = 1; m < 8; ++m) {
                        sum += *reinterpret_cast<const float4*>(&Hb[HIDX(hcc, hr0 + m + 8, hjj)])
                             - *reinterpret_cast<const float4*>(&Hb[HIDX(hcc, hr0 + m - 1, hjj)]);
                        *reinterpret_cast<float4*>(&Ue[UIDX(hcc, hr0 + m, hjj)]) = sum;
                    }
                }
                barrier_novm();           // loads stay in flight across this
            }
        }
    }

    // ---- block reduction: wave shuffle, then 4 partials via LDS ----
    __syncthreads();                      // full drain before reuse of LDS
    #pragma unroll
    for (int off = 32; off > 0; off >>= 1)
        acc += __shfl_down(acc, off, 64);
    const int wave = t >> 6;
    if ((t & 63) == 0) wsum[wave] = acc;
    __syncthreads();
    if (t == 0) {
        const float s = wsum[0] + wsum[1] + wsum[2] + wsum[3];
        atomicAdd(out, -s * (1.0f / 8192000.0f));
    }
}

extern "C" void kernel_launch(void* const* d_in, const int* in_sizes, int n_in,
                              void* d_out, int out_size, void* d_ws, size_t ws_size,
                              hipStream_t stream)
{
    const float* x = (const float*)d_in[0];
    const float* y = (const float*)d_in[1];
    float* out = (float*)d_out;

    // d_out is poisoned 0xAA before every call; accumulate atomically on zero
    hipMemsetAsync(out, 0, sizeof(float), stream);

    dim3 grid(DIM / TW, DIM / TH, 2 * (DIM / CD));  // 10 x 10 x 16 = 1600 blocks
    lncc_kernel<<<grid, 256, 0, stream>>>(x, y, out);
}

// Round 9
// 170.989 us; speedup vs baseline: 2.1239x; 1.0663x over previous
//
#include <hip/hip_runtime.h>

#define DIM 160
#define SLICE (DIM * DIM)
#define TH 16
#define TW 16
#define CD 40         // output slices per block chunk; 160/CD = 4 chunks/batch
#define NS (CD + 8)   // 48 input slices; iterations i = 0..NS+1

// Fused LNCC, separable w -> h -> d. Evidence through R7:
//  - per-slice-instance cost ~1500-1660cy/CU across 3-, 2-, 1-barrier
//    structures: barrier count / role overlap / LDS throughput / occupancy
//    all ruled out as limiters.
//  - surviving theory: exposed vmem latency. Loads issued ~300cy before the
//    loader wave's vmcnt wait in wsums; L3/HBM latency 450-900cy; ~2
//    co-resident blocks can't cover it. R6 (deep prefetch) raised delivered
//    BW to 2.4TB/s but spilled (launch_bounds(256,4) forced 64 VGPR).
//  This version: R7's validated 1-barrier pipelined skeleton + R6's parity
//  double-buffered carried loads, at the proven (256,2) register envelope.
//  Loads for slice i+2 issue right after parity set (i&1) is consumed at
//  slice i => ~2 iterations (~3000cy) of latency cover, 12 loads in flight
//  per loader thread. VGPR ~84+24 = ~110 < 128, no spill expected.
// Per iteration i (ONE barrier):
//   ring(slice i-2, reads U[i&1])
//   || loaders t>=160: w-sum(slice i) from parity set -> H[i&1],
//      then issue loads(slice i+2) into the same parity set
//   || h-sum t<40: H[(i-1)&1] -> U[(i-1)&1]
//   then barrier_novm (loads stay in flight across it).
// 18-deep unroll (even, = 0 mod 9) keeps ring phase AND parity compile-time.
#define HP 492        // H plane stride (24*20 + 12 pad; 16B-aligned)
#define HR 20         // H row stride (16 used cols + 4)
#define HIDX(c,i,j) ((c)*HP + (i)*HR + (j))
#define UIDX(c,i,j) ((c)*260 + (i)*16 + (j))   // U: 16x16 plane (+4 pad)

// 9-tap sliding window over 12 consecutive values -> 4 outputs
#define WSLIDE(dst, V0,V1,V2,V3,V4,V5,V6,V7,V8,V9,V10,V11) do {            \
    float s_ = (V0)+(V1)+(V2)+(V3)+(V4)+(V5)+(V6)+(V7)+(V8);               \
    float4 o_; o_.x = s_;                                                  \
    s_ += (V9)  - (V0); o_.y = s_;                                         \
    s_ += (V10) - (V1); o_.z = s_;                                         \
    s_ += (V11) - (V2); o_.w = s_;                                         \
    (dst) = o_; } while (0)

// Barrier that does NOT drain vmcnt: LDS producers/consumers are ordered by
// lgkmcnt(0); global loads issued before it stay in flight (T4 pattern).
static __device__ __forceinline__ void barrier_novm()
{
    asm volatile("s_waitcnt lgkmcnt(0)" ::: "memory");
    __builtin_amdgcn_s_barrier();
    asm volatile("" ::: "memory");
}

__global__ __launch_bounds__(256, 2)
void lncc_kernel(const float* __restrict__ x, const float* __restrict__ y,
                 float* __restrict__ out)
{
    __shared__ __align__(16) float H[2][5 * HP];
    __shared__ __align__(16) float U[2][5 * 260];
    __shared__ float wsum[4];

    const int t  = threadIdx.x;
    const int w0 = blockIdx.x * TW;
    const int h0 = blockIdx.y * TH;
    const int bz = blockIdx.z;
    const int b   = bz >> 2;              // batch
    const int zo0 = (bz & 3) * CD;        // first output slice of chunk

    const float* xb = x + (size_t)b * (DIM * SLICE);
    const float* yb = y + (size_t)b * (DIM * SLICE);

    // ---- loader role (t in [160,256)): (halo row lrw, output col-quad lq) ----
    const int lt  = t - 160;              // 0..95
    const int lrw = lt >> 2;              // 0..23
    const int lq  = lt & 3;               // 0..3
    const int ghr = min(max(h0 - 4 + lrw, 0), DIM - 1);
    const int rowoff = ghr * DIM;
    const int gws = w0 + 4 * lq - 4;      // first of 12 input cols (aligned)
    // quad 1 (cols gws+4..gws+7) is always in-bounds; quads 0/2 clamp at edges
    const bool ok0 = (gws >= 0);
    const bool ok2 = (gws + 8 <= DIM - 4);
    const int jj = 4 * lq;

    // ---- h-sum role (t < 40): (channel hcc, col-quad hq, row-half hh) ----
    const int hcc = t >> 3;               // 0..4
    const int hq  = (t >> 1) & 3;         // 0..3
    const int hh  = t & 1;                // 0..1
    const int hr0 = hh * 8;
    const int hjj = 4 * hq;

    // ---- ring role: one output column each ----
    const int i4 = t >> 4;
    const int j4 = t & 15;

    float hist[9][5];                     // register ring (constant indices)
    float rs[5] = {0.f, 0.f, 0.f, 0.f, 0.f};
    float acc = 0.f;

    // two parity sets of carried loads (48 VGPR in loader threads)
    float4 eX0, eX1, eX2, eY0, eY1, eY2;  // even-i slices
    float4 oX0, oX1, oX2, oY0, oY1, oY2;  // odd-i slices

    auto issue_into = [&](int zsl, float4& X0, float4& X1, float4& X2,
                                   float4& Y0, float4& Y1, float4& Y2) {
        const float* xs = xb + (size_t)zsl * SLICE + rowoff;
        const float* ys = yb + (size_t)zsl * SLICE + rowoff;
        X1 = *reinterpret_cast<const float4*>(xs + gws + 4);
        Y1 = *reinterpret_cast<const float4*>(ys + gws + 4);
        if (ok0) {
            X0 = *reinterpret_cast<const float4*>(xs + gws);
            Y0 = *reinterpret_cast<const float4*>(ys + gws);
        } else {
            const float v = xs[0];       X0 = make_float4(v, v, v, v);
            const float w = ys[0];       Y0 = make_float4(w, w, w, w);
        }
        if (ok2) {
            X2 = *reinterpret_cast<const float4*>(xs + gws + 8);
            Y2 = *reinterpret_cast<const float4*>(ys + gws + 8);
        } else {
            const float v = xs[DIM - 1]; X2 = make_float4(v, v, v, v);
            const float w = ys[DIM - 1]; Y2 = make_float4(w, w, w, w);
        }
    };

    auto wsums_to = [&](float* Hb,
                        const float4& X0, const float4& X1, const float4& X2,
                        const float4& Y0, const float4& Y1, const float4& Y2) {
        float4 o;
        WSLIDE(o, X0.x,X0.y,X0.z,X0.w, X1.x,X1.y,X1.z,X1.w, X2.x,X2.y,X2.z,X2.w);
        *reinterpret_cast<float4*>(&Hb[HIDX(0, lrw, jj)]) = o;
        WSLIDE(o, Y0.x,Y0.y,Y0.z,Y0.w, Y1.x,Y1.y,Y1.z,Y1.w, Y2.x,Y2.y,Y2.z,Y2.w);
        *reinterpret_cast<float4*>(&Hb[HIDX(1, lrw, jj)]) = o;
        float4 a0 = X0 * X0, a1 = X1 * X1, a2 = X2 * X2;
        WSLIDE(o, a0.x,a0.y,a0.z,a0.w, a1.x,a1.y,a1.z,a1.w, a2.x,a2.y,a2.z,a2.w);
        *reinterpret_cast<float4*>(&Hb[HIDX(2, lrw, jj)]) = o;
        a0 = Y0 * Y0; a1 = Y1 * Y1; a2 = Y2 * Y2;
        WSLIDE(o, a0.x,a0.y,a0.z,a0.w, a1.x,a1.y,a1.z,a1.w, a2.x,a2.y,a2.z,a2.w);
        *reinterpret_cast<float4*>(&Hb[HIDX(3, lrw, jj)]) = o;
        a0 = X0 * Y0; a1 = X1 * Y1; a2 = X2 * Y2;
        WSLIDE(o, a0.x,a0.y,a0.z,a0.w, a1.x,a1.y,a1.z,a1.w, a2.x,a2.y,a2.z,a2.w);
        *reinterpret_cast<float4*>(&Hb[HIDX(4, lrw, jj)]) = o;
    };

    const int zfirst = zo0 - 4;           // slices 0..NS-1 <-> z = zfirst+...
    auto zclamp = [&](int sl) { return min(max(zfirst + sl, 0), DIM - 1); };
    if (t >= 160) {
        issue_into(zclamp(0), eX0, eX1, eX2, eY0, eY1, eY2);
        issue_into(zclamp(1), oX0, oX1, oX2, oY0, oY1, oY2);
    }

    // iteration i: ring(i-2) || w-sum(i)->H[i&1] + issue loads(i+2) into the
    // just-consumed parity set || h-sum H[(i-1)&1] -> U[(i-1)&1]; ONE barrier.
    // i = 0..NS+1. 18-unroll: i&1 == p&1 and (i-2)%9 == (p+7)%9, both static.
    for (int base = 0; base < 54; base += 18) {
        #pragma unroll
        for (int p = 0; p < 18; ++p) {
            const int i = base + p;
            if (i <= NS + 1) {
                // ---- ring: slice i-2 (reads U[i&1], written last iteration)
                if (i >= 2) {
                    const float* Ub = U[p & 1];
                    const int cp = (p + 7) % 9;   // (i-2) mod 9, compile-time
                    float u[5];
                    #pragma unroll
                    for (int c = 0; c < 5; ++c) {
                        u[c] = Ub[UIDX(c, i4, j4)];
                        rs[c] += u[c];
                        hist[cp][c] = u[c];
                    }
                    if (i >= 10) {        // window of 9 slices complete
                        const float inv = 1.0f / 729.0f;
                        const float xm = rs[0] * inv, ym = rs[1] * inv;
                        const float x2 = rs[2] * inv, y2 = rs[3] * inv;
                        const float xy = rs[4] * inv;
                        const float cross = xy - xm * ym;
                        const float vx = x2 - xm * xm;
                        const float vy = y2 - ym * ym;
                        acc += cross * cross / (vx * vy + 1e-5f);
                        const int po = (cp + 1) % 9;  // slice leaving window
                        #pragma unroll
                        for (int c = 0; c < 5; ++c)
                            rs[c] -= hist[po][c];
                    }
                }
                // ---- loaders: w-sum slice i from parity set -> H[i&1],
                //      then refill the same set with loads for slice i+2
                if (i <= NS - 1 && t >= 160) {
                    if ((p & 1) == 0) {
                        wsums_to(H[0], eX0, eX1, eX2, eY0, eY1, eY2);
                        if (i <= NS - 3)
                            issue_into(zclamp(i + 2), eX0, eX1, eX2, eY0, eY1, eY2);
                    } else {
                        wsums_to(H[1], oX0, oX1, oX2, oY0, oY1, oY2);
                        if (i <= NS - 3)
                            issue_into(zclamp(i + 2), oX0, oX1, oX2, oY0, oY1, oY2);
                    }
                }
                // ---- h-sum: slice i-1, H[(i-1)&1] -> U[(i-1)&1]
                if (i >= 1 && i <= NS && t < 40) {
                    const float* Hb = H[(p + 1) & 1];
                    float* Ue = U[(p + 1) & 1];
                    float4 sum = make_float4(0.f, 0.f, 0.f, 0.f);
                    #pragma unroll
                    for (int k = 0; k < 9; ++k)
                        sum += *reinterpret_cast<const float4*>(&Hb[HIDX(hcc, hr0 + k, hjj)]);
                    *reinterpret_cast<float4*>(&Ue[UIDX(hcc, hr0, hjj)]) = sum;
                    #pragma unroll
                    for (int m = 1; m < 8; ++m) {
                        sum += *reinterpret_cast<const float4*>(&Hb[HIDX(hcc, hr0 + m + 8, hjj)])
                             - *reinterpret_cast<const float4*>(&Hb[HIDX(hcc, hr0 + m - 1, hjj)]);
                        *reinterpret_cast<float4*>(&Ue[UIDX(hcc, hr0 + m, hjj)]) = sum;
                    }
                }
                barrier_novm();           // loads stay in flight across this
            }
        }
    }

    // ---- block reduction: wave shuffle, then 4 partials via LDS ----
    __syncthreads();                      // full drain before reuse of LDS
    #pragma unroll
    for (int off = 32; off > 0; off >>= 1)
        acc += __shfl_down(acc, off, 64);
    const int wave = t >> 6;
    if ((t & 63) == 0) wsum[wave] = acc;
    __syncthreads();
    if (t == 0) {
        const float s = wsum[0] + wsum[1] + wsum[2] + wsum[3];
        atomicAdd(out, -s * (1.0f / 8192000.0f));
    }
}

extern "C" void kernel_launch(void* const* d_in, const int* in_sizes, int n_in,
                              void* d_out, int out_size, void* d_ws, size_t ws_size,
                              hipStream_t stream)
{
    const float* x = (const float*)d_in[0];
    const float* y = (const float*)d_in[1];
    float* out = (float*)d_out;

    // d_out is poisoned 0xAA before every call; accumulate atomically on zero
    hipMemsetAsync(out, 0, sizeof(float), stream);

    dim3 grid(DIM / TW, DIM / TH, 2 * (DIM / CD));  // 10 x 10 x 8 = 800 blocks
    lncc_kernel<<<grid, 256, 0, stream>>>(x, y, out);
}